// Round 1
// baseline (833.826 us; speedup 1.0000x reference)
//
#include <hip/hip_runtime.h>

// Encoder_8718783611479: stateless per-step LSTMCell => one GEMM + elementwise.
//   gates = xt @ W_ih^T (+ b_ih + b_hh), only i,g,o gates live (f * c_prev = 0)
//   out = sigmoid(sigmoid(o_g)*tanh(sigmoid(i_g)*tanh(g_g)))
// xt[b,t,k] = x[b*43200 + k*240 + t]  (K=180 strided, M=t contiguous)

#define B_SZ 2048
#define T_SZ 240
#define K_SZ 180
#define H_SZ 90

typedef __bf16 bf16x8 __attribute__((ext_vector_type(8)));
typedef float f32x4 __attribute__((ext_vector_type(4)));

__device__ __forceinline__ __bf16 f2bf(float f) {
    union { float f; unsigned u; } a; a.f = f;
    unsigned r = (a.u + 0x7FFFu + ((a.u >> 16) & 1u)) >> 16;  // RNE
    union { unsigned short s; __bf16 b; } o; o.s = (unsigned short)r;
    return o.b;
}

__device__ __forceinline__ float sigmoidf_(float x) {
    return 1.0f / (1.0f + __expf(-x));
}
__device__ __forceinline__ float tanhf_(float x) {
    return 1.0f - 2.0f / (__expf(2.0f * x) + 1.0f);
}

__global__ __launch_bounds__(384, 3) void lstm_fused_kernel(
    const float* __restrict__ x,
    const float* __restrict__ W_ih,
    const float* __restrict__ b_ih,
    const float* __restrict__ b_hh,
    float* __restrict__ out)
{
    const int b    = blockIdx.x;
    const int tid  = threadIdx.x;
    const int wave = tid >> 6;      // 0..5 -> h-tile
    const int lane = tid & 63;
    const int q    = lane >> 4;     // quad 0..3
    const int n    = lane & 15;
    const int h    = wave * 16 + n; // output column; valid if < 90
    const bool hv  = (h < H_SZ);

    // ---- B fragments (W^T), in registers for the whole kernel ----
    // B[k][n] = W_ih[gatebase+h][k]; per-lane j: k = ks*32 + q*8 + j
    bf16x8 bfrag[3][6];
    const int gatebase[3] = {0, 180, 270};   // i, g, o rows of W_ih
    #pragma unroll
    for (int g = 0; g < 3; ++g) {
        const float* wrow = W_ih + (size_t)(gatebase[g] + (hv ? h : 0)) * K_SZ;
        #pragma unroll
        for (int ks = 0; ks < 6; ++ks) {
            bf16x8 f;
            #pragma unroll
            for (int j = 0; j < 8; ++j) {
                int k = ks * 32 + q * 8 + j;
                float v = (hv && k < K_SZ) ? wrow[k] : 0.0f;
                f[j] = f2bf(v);
            }
            bfrag[g][ks] = f;
        }
    }

    float bias_i = hv ? (b_ih[h]       + b_hh[h])       : 0.0f;
    float bias_g = hv ? (b_ih[180 + h] + b_hh[180 + h]) : 0.0f;
    float bias_o = hv ? (b_ih[270 + h] + b_hh[270 + h]) : 0.0f;

    const float* xb = x   + (size_t)b * (K_SZ * T_SZ);
    float*       ob = out + (size_t)b * (T_SZ * H_SZ);

    #pragma unroll 1
    for (int mt = 0; mt < 15; ++mt) {
        // A fragments: A[m=n][k] = xb[k*240 + mt*16 + n]
        bf16x8 afrag[6];
        #pragma unroll
        for (int ks = 0; ks < 6; ++ks) {
            bf16x8 f;
            #pragma unroll
            for (int j = 0; j < 8; ++j) {
                int k = ks * 32 + q * 8 + j;
                float v = (k < K_SZ) ? xb[k * T_SZ + mt * 16 + n] : 0.0f;
                f[j] = f2bf(v);
            }
            afrag[ks] = f;
        }

        f32x4 acc0 = {0.f,0.f,0.f,0.f};
        f32x4 acc1 = {0.f,0.f,0.f,0.f};
        f32x4 acc2 = {0.f,0.f,0.f,0.f};
        #pragma unroll
        for (int ks = 0; ks < 6; ++ks) {
            acc0 = __builtin_amdgcn_mfma_f32_16x16x32_bf16(afrag[ks], bfrag[0][ks], acc0, 0, 0, 0);
            acc1 = __builtin_amdgcn_mfma_f32_16x16x32_bf16(afrag[ks], bfrag[1][ks], acc1, 0, 0, 0);
            acc2 = __builtin_amdgcn_mfma_f32_16x16x32_bf16(afrag[ks], bfrag[2][ks], acc2, 0, 0, 0);
        }

        // Epilogue: C/D layout col=lane&15 (=h), row=q*4+e (=t within tile)
        #pragma unroll
        for (int e = 0; e < 4; ++e) {
            int t = mt * 16 + q * 4 + e;
            float gi = acc0[e] + bias_i;
            float gg = acc1[e] + bias_g;
            float go = acc2[e] + bias_o;
            float c  = sigmoidf_(gi) * tanhf_(gg);
            float hh = sigmoidf_(go) * tanhf_(c);
            float v  = sigmoidf_(hh);
            if (hv) ob[t * H_SZ + h] = v;
        }
    }
}

extern "C" void kernel_launch(void* const* d_in, const int* in_sizes, int n_in,
                              void* d_out, int out_size, void* d_ws, size_t ws_size,
                              hipStream_t stream) {
    const float* x    = (const float*)d_in[0];
    const float* W_ih = (const float*)d_in[1];
    // d_in[2] = W_hh: dead (h0 = c0 = 0 at every timestep)
    const float* b_ih = (const float*)d_in[3];
    const float* b_hh = (const float*)d_in[4];
    float* out = (float*)d_out;

    lstm_fused_kernel<<<dim3(B_SZ), dim3(384), 0, stream>>>(x, W_ih, b_ih, b_hh, out);
}